// Round 5
// baseline (44.150 us; speedup 1.0000x reference)
//
#include <hip/hip_runtime.h>
#include <hip/hip_bf16.h>

// B=2, N=768, D_IN=D_OUT=64, TEMP=2, BN_EPS=1e-5
constexpr int Bc = 2;
constexpr int Nc = 768;
constexpr int Dc = 64;
constexpr int NPAIR = Nc / 2;          // 384 row-pairs per batch

typedef __attribute__((ext_vector_type(8))) short short8;   // 8 bf16 (4 VGPRs)
typedef __attribute__((ext_vector_type(4))) short short4v;  // 4 bf16
typedef __attribute__((ext_vector_type(4))) float f32x4;    // MFMA C/D frag

// tanh(u) = 1 - 2*rcp(exp2(u*2log2e)+1)
#define TWO_LOG2E 2.8853900817779268f
// (half_sum_aw - p) ALREADY includes the /TEMP (tanh-identity halving).
// Only convert to exp2 domain: scale by log2(e). [R4 bug: used log2e/2 -> double /TEMP]
#define SCORE_SCALE 1.4426950408889634f

__device__ inline short fbf(float f) {
    __hip_bfloat16 h = __float2bfloat16(f);
    return *reinterpret_cast<short*>(&h);
}

// ---------------- prep: x f32 -> bf16 into ws ----------------
__global__ __launch_bounds__(256)
void prep_kernel(const float* __restrict__ x, short* __restrict__ xb)
{
    const int idx = blockIdx.x * 256 + threadIdx.x;   // 24576 float4s
    const float4 v = ((const float4*)x)[idx];
    short4v o;
    o[0] = fbf(v.x); o[1] = fbf(v.y); o[2] = fbf(v.z); o[3] = fbf(v.w);
    ((short4v*)xb)[idx] = o;
}

// ---------------- scores: pair-row balanced, symmetric, mirror writes ----------------
// Block = one half of pair-row (i1=q, i2=767-q): 49 tiles split 25/24.
__global__ __launch_bounds__(256, 4)
void scores_kernel(const float* __restrict__ x,
                   const short* __restrict__ xbf,
                   const float* __restrict__ W_att,
                   const float* __restrict__ b_att,
                   const float* __restrict__ a_w,
                   float* __restrict__ sc)
{
    __shared__ short s_A[2][Dc * Dc];  // both rows' swizzled A (16 KB)
    __shared__ float s_xr[2][Dc];

    const int blk  = blockIdx.x;       // [0, 1536)
    const int pr   = blk >> 1;
    const int half = blk & 1;
    const int b    = pr / NPAIR;
    const int q    = pr - b * NPAIR;
    const int i1   = q;
    const int i2   = Nc - 1 - q;
    const int c1   = 48 - (i1 >> 4);   // tiles in row i1; row i2 has 49-c1

    const int tid  = threadIdx.x;
    const int lane = tid & 63;
    const int wid  = tid >> 6;

    const float* xb  = x   + (size_t)b * Nc * Dc;
    const short* xbb = xbf + (size_t)b * Nc * Dc;

    if (tid < 2 * Dc) {
        const int r = tid >> 6;        // 0 -> i1, 1 -> i2
        s_xr[r][tid & 63] = xb[(r ? i2 : i1) * Dc + (tid & 63)];
    }
    __syncthreads();

    // build both swizzled A matrices: A[r][o][d] = x_r[d]*W_att[d][o]; phys chunk = c ^ (o&7)
#pragma unroll
    for (int rsel = 0; rsel < 2; ++rsel) {
        const int d0 = wid * 16;
        float m0[16];
#pragma unroll
        for (int dd = 0; dd < 16; ++dd)
            m0[dd] = s_xr[rsel][d0 + dd] * W_att[(d0 + dd) * Dc + lane];
#pragma unroll
        for (int c8 = 0; c8 < 2; ++c8) {
            short8 v;
#pragma unroll
            for (int e = 0; e < 8; ++e) v[e] = fbf(m0[c8 * 8 + e]);
            const int c    = wid * 2 + c8;
            const int phys = c ^ (lane & 7);
            *(short8*)(&s_A[rsel][lane * Dc + phys * 8]) = v;
        }
    }

    // per-lane constants for this lane's 16 o's (o = 16*mt + 4*(lane>>4) + r)
    float tb2[16], aw[16];
#pragma unroll
    for (int mt = 0; mt < 4; ++mt)
#pragma unroll
        for (int r = 0; r < 4; ++r) {
            const int o = 16 * mt + 4 * (lane >> 4) + r;
            tb2[mt * 4 + r] = TWO_LOG2E * b_att[o];
            aw [mt * 4 + r] = a_w[o];
        }
    float sa = 0.f;
#pragma unroll
    for (int k = 0; k < 16; ++k) sa += aw[k];
    sa += __shfl_xor(sa, 16, 64);
    sa += __shfl_xor(sa, 32, 64);
    const float half_sum_aw = 0.5f * sa;
    __syncthreads();

    // global tile index g over the 49-tile pair-row; this block's span:
    const int gend = 25 + half * 24;   // half0: [0,25), half1: [25,49)
    int g = half * 25 + wid;

    if (g < gend) {
        // tile (j-block) for a given g — row i1 first, then row i2
        auto tile_of = [&](int gg) {
            return (gg < c1) ? (i1 >> 4) + gg : (i2 >> 4) + (gg - c1);
        };

        int t = tile_of(g);
        const short* p0 = xbb + (size_t)(16 * t + (lane & 15)) * Dc + (lane >> 4) * 8;
        short8 cb0 = *(const short8*)p0;
        short8 cb1 = *(const short8*)(p0 + 32);

        int cur = -1;
        short8 afr[4][2];

        while (g < gend) {
            const int rsel = (g >= c1) ? 1 : 0;          // wave-uniform
            if (rsel != cur) {                           // (re)load A-frags
#pragma unroll
                for (int mt = 0; mt < 4; ++mt)
#pragma unroll
                    for (int kt = 0; kt < 2; ++kt) {
                        const int o    = 16 * mt + (lane & 15);
                        const int c    = (lane >> 4) + 4 * kt;
                        const int phys = c ^ (o & 7);
                        afr[mt][kt] = *(const short8*)(&s_A[rsel][o * Dc + phys * 8]);
                    }
                cur = rsel;
            }

            const int gn = g + 4;
            int tn = 0;
            short8 n0, n1;
            if (gn < gend) {
                tn = tile_of(gn);
                const short* p1 = xbb + (size_t)(16 * tn + (lane & 15)) * Dc + (lane >> 4) * 8;
                n0 = *(const short8*)p1;
                n1 = *(const short8*)(p1 + 32);
            }

            f32x4 ac[4];
#pragma unroll
            for (int mt = 0; mt < 4; ++mt) {
                ac[mt] = (f32x4){0.f, 0.f, 0.f, 0.f};
                ac[mt] = __builtin_amdgcn_mfma_f32_16x16x32_bf16(afr[mt][0], cb0, ac[mt], 0, 0, 0);
                ac[mt] = __builtin_amdgcn_mfma_f32_16x16x32_bf16(afr[mt][1], cb1, ac[mt], 0, 0, 0);
            }

            float p = 0.f;
#pragma unroll
            for (int mt = 0; mt < 4; ++mt)
#pragma unroll
                for (int r = 0; r < 4; ++r) {
                    const float m  = fmaf(ac[mt][r], TWO_LOG2E, tb2[mt * 4 + r]);
                    const float e  = __builtin_amdgcn_exp2f(m);
                    const float rc = __builtin_amdgcn_rcpf(e + 1.f);
                    p = fmaf(aw[mt * 4 + r], rc, p);
                }
            p += __shfl_xor(p, 16, 64);
            p += __shfl_xor(p, 32, 64);

            const int ic = rsel ? i2 : i1;
            const int j  = 16 * t + lane;
            if (lane < 16) {
                const float v = (half_sum_aw - p) * SCORE_SCALE;
                if (j >= ic) sc[((size_t)b * Nc + ic) * Nc + j] = v;
                if (j >  ic) sc[((size_t)b * Nc + j) * Nc + ic] = v;   // mirror
            }
            cb0 = n0; cb1 = n1; g = gn; t = tn;
        }
    }
}

// ---------------- finish: coalesced row softmax + agg + proj + BN + SELU ----------------
__global__ __launch_bounds__(256, 4)
void finish_kernel(const float* __restrict__ x,
                   const float* __restrict__ sc,
                   const float* __restrict__ W_p,
                   const float* __restrict__ b_p,
                   const float* __restrict__ W_q,
                   const float* __restrict__ b_q,
                   const float* __restrict__ gamma,
                   const float* __restrict__ beta,
                   const float* __restrict__ r_mean,
                   const float* __restrict__ r_var,
                   float* __restrict__ out)
{
    __shared__ float s_score[Nc];
    __shared__ float s_xi[Dc];
    __shared__ float s_red[4][Dc];
    __shared__ float s_tmp[4];

    const int blk = blockIdx.x;
    const int b   = blk & 1;
    const int i   = blk >> 1;
    const int tid  = threadIdx.x;
    const int lane = tid & 63;
    const int wid  = tid >> 6;

    const float* xb = x + (size_t)b * Nc * Dc;
    if (tid < Dc) s_xi[tid] = xb[i * Dc + tid];

    // full row, coalesced (mirror writes made it complete)
    const float* srow = sc + ((size_t)b * Nc + i) * Nc;
    for (int j = tid; j < Nc; j += 256) s_score[j] = srow[j];
    __syncthreads();

    // softmax over 768 (scores pre-scaled: exp2 domain)
    float mx = -1e30f;
    for (int j = tid; j < Nc; j += 256) mx = fmaxf(mx, s_score[j]);
#pragma unroll
    for (int off = 32; off; off >>= 1)
        mx = fmaxf(mx, __shfl_xor(mx, off, 64));
    if (lane == 0) s_tmp[wid] = mx;
    __syncthreads();
    mx = fmaxf(fmaxf(s_tmp[0], s_tmp[1]), fmaxf(s_tmp[2], s_tmp[3]));
    __syncthreads();

    float sm = 0.f;
    for (int j = tid; j < Nc; j += 256) {
        const float e = __builtin_amdgcn_exp2f(s_score[j] - mx);
        s_score[j] = e;
        sm += e;
    }
#pragma unroll
    for (int off = 32; off; off >>= 1)
        sm += __shfl_xor(sm, off, 64);
    if (lane == 0) s_tmp[wid] = sm;
    __syncthreads();
    const float inv_sum = 1.f / (s_tmp[0] + s_tmp[1] + s_tmp[2] + s_tmp[3]);

    // agg[d] = sum_j att[j]*x[b,j,d]; lane = d
    float aggp = 0.f;
    const int j0 = wid * (Nc / 4), j1 = j0 + Nc / 4;
    for (int j = j0; j < j1; ++j)
        aggp = fmaf(s_score[j], xb[j * Dc + lane], aggp);
    s_red[wid][lane] = aggp;
    __syncthreads();

    if (wid == 0)
        s_red[0][lane] = (s_red[0][lane] + s_red[1][lane] +
                          s_red[2][lane] + s_red[3][lane]) * inv_sum;
    __syncthreads();

    if (wid == 0) {
        float y = b_p[lane] + b_q[lane];
#pragma unroll 8
        for (int d = 0; d < Dc; ++d) {
            y = fmaf(s_red[0][d], W_p[d * Dc + lane], y);
            y = fmaf(s_xi[d],     W_q[d * Dc + lane], y);
        }
        const float inv_std = rsqrtf(r_var[lane] + 1e-5f);
        y = (y - r_mean[lane]) * (gamma[lane] * inv_std) + beta[lane];
        const float kScale = 1.0507009873554805f;
        const float kAlpha = 1.6732632423543772f;
        y = y > 0.f ? kScale * y : kScale * kAlpha * (__expf(y) - 1.f);
        out[((size_t)b * Nc + i) * Dc + lane] = y;
    }
}

// ---------------- fallback: R2 mono-kernel (used only if ws too small) ----------------
__global__ __launch_bounds__(256, 4)
void mono_kernel(const float* __restrict__ x,
                 const float* __restrict__ W_att,
                 const float* __restrict__ b_att,
                 const float* __restrict__ a_w,
                 const float* __restrict__ W_p,
                 const float* __restrict__ b_p,
                 const float* __restrict__ W_q,
                 const float* __restrict__ b_q,
                 const float* __restrict__ gamma,
                 const float* __restrict__ beta,
                 const float* __restrict__ r_mean,
                 const float* __restrict__ r_var,
                 float* __restrict__ out)
{
    __shared__ short s_A[Dc * Dc];
    __shared__ float s_score[Nc];
    __shared__ float s_xi[Dc];
    __shared__ float s_red[4][Dc];
    __shared__ float s_tmp[4];

    const int bid = blockIdx.x;
    const int b   = bid / Nc;
    const int i   = bid - b * Nc;
    const int tid  = threadIdx.x;
    const int lane = tid & 63;
    const int wid  = tid >> 6;

    const float* xb = x + (size_t)b * Nc * Dc;
    if (tid < Dc) s_xi[tid] = xb[i * Dc + tid];
    __syncthreads();

    {
        const int d0 = wid * 16;
        float m0[16];
#pragma unroll
        for (int dd = 0; dd < 16; ++dd)
            m0[dd] = s_xi[d0 + dd] * W_att[(d0 + dd) * Dc + lane];
#pragma unroll
        for (int c8 = 0; c8 < 2; ++c8) {
            short8 v;
#pragma unroll
            for (int e = 0; e < 8; ++e) v[e] = fbf(m0[c8 * 8 + e]);
            const int c    = wid * 2 + c8;
            const int phys = c ^ (lane & 7);
            *(short8*)(&s_A[lane * Dc + phys * 8]) = v;
        }
    }

    float tb[16], aw[16];
#pragma unroll
    for (int mt = 0; mt < 4; ++mt)
#pragma unroll
        for (int r = 0; r < 4; ++r) {
            const int o = 16 * mt + 4 * (lane >> 4) + r;
            tb[mt * 4 + r] = 2.f * b_att[o];
            aw[mt * 4 + r] = a_w[o];
        }
    __syncthreads();

    short8 afr[4][2];
#pragma unroll
    for (int mt = 0; mt < 4; ++mt)
#pragma unroll
        for (int kt = 0; kt < 2; ++kt) {
            const int o    = 16 * mt + (lane & 15);
            const int c    = (lane >> 4) + 4 * kt;
            const int phys = c ^ (o & 7);
            afr[mt][kt] = *(const short8*)(&s_A[o * Dc + phys * 8]);
        }

    const int jbase = wid * 192;
    for (int t = 0; t < 12; ++t) {
        const int j0 = jbase + t * 16;
        const float* xr = xb + (size_t)(j0 + (lane & 15)) * Dc + (lane >> 4) * 8;
        const float4 v0 = *(const float4*)(xr);
        const float4 v1 = *(const float4*)(xr + 4);
        const float4 v2 = *(const float4*)(xr + 32);
        const float4 v3 = *(const float4*)(xr + 36);
        short8 bf0, bf1;
        bf0[0]=fbf(v0.x); bf0[1]=fbf(v0.y); bf0[2]=fbf(v0.z); bf0[3]=fbf(v0.w);
        bf0[4]=fbf(v1.x); bf0[5]=fbf(v1.y); bf0[6]=fbf(v1.z); bf0[7]=fbf(v1.w);
        bf1[0]=fbf(v2.x); bf1[1]=fbf(v2.y); bf1[2]=fbf(v2.z); bf1[3]=fbf(v2.w);
        bf1[4]=fbf(v3.x); bf1[5]=fbf(v3.y); bf1[6]=fbf(v3.z); bf1[7]=fbf(v3.w);

        f32x4 ac[4];
#pragma unroll
        for (int mt = 0; mt < 4; ++mt) {
            ac[mt] = (f32x4){0.f, 0.f, 0.f, 0.f};
            ac[mt] = __builtin_amdgcn_mfma_f32_16x16x32_bf16(afr[mt][0], bf0, ac[mt], 0, 0, 0);
            ac[mt] = __builtin_amdgcn_mfma_f32_16x16x32_bf16(afr[mt][1], bf1, ac[mt], 0, 0, 0);
        }

        float p = 0.f;
#pragma unroll
        for (int mt = 0; mt < 4; ++mt)
#pragma unroll
            for (int r = 0; r < 4; ++r) {
                const float e  = __expf(fmaf(ac[mt][r], 2.f, tb[mt * 4 + r]));
                const float th = 1.f - 2.f * __builtin_amdgcn_rcpf(e + 1.f);
                p = fmaf(th, aw[mt * 4 + r], p);
            }
        p += __shfl_xor(p, 16, 64);
        p += __shfl_xor(p, 32, 64);
        if (lane < 16) s_score[j0 + lane] = p * 0.5f;
    }
    __syncthreads();

    float mx = -1e30f;
    for (int j = tid; j < Nc; j += 256) mx = fmaxf(mx, s_score[j]);
#pragma unroll
    for (int off = 32; off; off >>= 1)
        mx = fmaxf(mx, __shfl_xor(mx, off, 64));
    if (lane == 0) s_tmp[wid] = mx;
    __syncthreads();
    mx = fmaxf(fmaxf(s_tmp[0], s_tmp[1]), fmaxf(s_tmp[2], s_tmp[3]));
    __syncthreads();

    float sm = 0.f;
    for (int j = tid; j < Nc; j += 256) {
        const float e = __expf(s_score[j] - mx);
        s_score[j] = e;
        sm += e;
    }
#pragma unroll
    for (int off = 32; off; off >>= 1)
        sm += __shfl_xor(sm, off, 64);
    if (lane == 0) s_tmp[wid] = sm;
    __syncthreads();
    const float inv_sum = 1.f / (s_tmp[0] + s_tmp[1] + s_tmp[2] + s_tmp[3]);

    float aggp = 0.f;
    const int j0 = wid * (Nc / 4), j1 = j0 + Nc / 4;
    for (int j = j0; j < j1; ++j)
        aggp = fmaf(s_score[j], xb[j * Dc + lane], aggp);
    s_red[wid][lane] = aggp;
    __syncthreads();

    if (wid == 0)
        s_red[0][lane] = (s_red[0][lane] + s_red[1][lane] +
                          s_red[2][lane] + s_red[3][lane]) * inv_sum;
    __syncthreads();

    if (wid == 0) {
        float y = b_p[lane] + b_q[lane];
#pragma unroll 8
        for (int d = 0; d < Dc; ++d) {
            y = fmaf(s_red[0][d], W_p[d * Dc + lane], y);
            y = fmaf(s_xi[d],     W_q[d * Dc + lane], y);
        }
        const float inv_std = rsqrtf(r_var[lane] + 1e-5f);
        y = (y - r_mean[lane]) * (gamma[lane] * inv_std) + beta[lane];
        const float kScale = 1.0507009873554805f;
        const float kAlpha = 1.6732632423543772f;
        y = y > 0.f ? kScale * y : kScale * kAlpha * (__expf(y) - 1.f);
        out[bid * Dc + lane] = y;
    }
}

extern "C" void kernel_launch(void* const* d_in, const int* in_sizes, int n_in,
                              void* d_out, int out_size, void* d_ws, size_t ws_size,
                              hipStream_t stream) {
    const float* x      = (const float*)d_in[0];
    const float* W_att  = (const float*)d_in[1];
    const float* b_att  = (const float*)d_in[2];
    const float* a_w    = (const float*)d_in[3];
    const float* W_p    = (const float*)d_in[4];
    const float* b_p    = (const float*)d_in[5];
    const float* W_q    = (const float*)d_in[6];
    const float* b_q    = (const float*)d_in[7];
    const float* gamma  = (const float*)d_in[8];
    const float* beta   = (const float*)d_in[9];
    const float* r_mean = (const float*)d_in[10];
    const float* r_var  = (const float*)d_in[11];
    float* out = (float*)d_out;

    constexpr size_t SC_OFF = 196608;                            // bf16 x: 2*768*64*2 B
    constexpr size_t NEED   = SC_OFF + (size_t)Bc * Nc * Nc * 4; // + f32 scores = 4,915,200 B

    if (ws_size >= NEED) {
        short* x_bf   = (short*)d_ws;
        float* scores = (float*)((char*)d_ws + SC_OFF);
        prep_kernel  <<<dim3((Bc * Nc * Dc / 4) / 256), dim3(256), 0, stream>>>(x, x_bf);
        scores_kernel<<<dim3(Bc * Nc), dim3(256), 0, stream>>>(x, x_bf, W_att, b_att, a_w, scores);
        finish_kernel<<<dim3(Bc * Nc), dim3(256), 0, stream>>>(x, scores, W_p, b_p, W_q, b_q,
                                                               gamma, beta, r_mean, r_var, out);
    } else {
        mono_kernel<<<dim3(Bc * Nc), dim3(256), 0, stream>>>(
            x, W_att, b_att, a_w, W_p, b_p, W_q, b_q,
            gamma, beta, r_mean, r_var, out);
    }
}